// Round 14
// baseline (287.766 us; speedup 1.0000x reference)
//
#include <hip/hip_runtime.h>
#include <hip/hip_fp16.h>

// ---------------------------------------------------------------------------
// GNN_6305011991202: 2-layer GraphSAGE (mean aggr) + linear head. fp32 I/O.
//   h1 = relu(mean1 @ W1_l^T + b1_l + x  @ W1_r^T)
//   h2 = relu(mean2 @ W2_l^T + b2_l + h1 @ W2_r^T)
//   out = h2 @ W3^T + b3          (out: [50000, 64] fp32)
// R14: gather tables split into two 3.2MB column-halves (each fits 4MB
// per-XCD L2). Per half: streaming warm phase (blocks striped by blockIdx&7
// ~ XCD round-robin) then gather at ~L2-hit rates. 64B rows -> 8 neighbors
// per wave-load. Diagnosis: R13 FETCH=51.6MB == 8 XCD x 6.4MB table (pure
// compulsory demand misses at 0.93 TB/s) — the L2 miss path was the floor.
// Keeps: f16 GEMMs, head fused into layer 2, fp8 e4m3 gather values.
// ---------------------------------------------------------------------------

typedef _Float16 f16x8 __attribute__((ext_vector_type(8)));
typedef float floatx4 __attribute__((ext_vector_type(4)));
typedef float floatx2 __attribute__((ext_vector_type(2)));

__device__ __forceinline__ unsigned short f2h(float f) {
    __half h = __float2half_rn(f);
    union { __half h; unsigned short s; } c; c.h = h; return c.s;
}
__device__ __forceinline__ __half2 u2h(unsigned u) {
    union { unsigned u; __half2 h; } c; c.u = u; return c.h;
}
__device__ __forceinline__ unsigned h2u(__half2 h) {
    union { __half2 h; unsigned u; } c; c.h = h; return c.u;
}
__device__ __forceinline__ __half2 shx(__half2 v, int m) {
    return u2h((unsigned)__shfl_xor((int)h2u(v), m, 64));
}
__device__ __forceinline__ ushort4 cvt4h(float4 v) {
    ushort4 o;
    o.x = f2h(v.x); o.y = f2h(v.y); o.z = f2h(v.z); o.w = f2h(v.w);
    return o;
}
__device__ __forceinline__ unsigned char f2fp8(float v) {
    return (unsigned char)(__builtin_amdgcn_cvt_pk_fp8_f32(v, v, 0, false) & 0xff);
}

// ---------------------------------------------------------------------------
// Fused prologue: convert 5 weight mats (f16, contiguous dst); x -> f16 and
// SPLIT fp8 tables (x8a cols 0-63, x8b cols 64-127, each [N,64]); zero deg.
#define WSEG 18432
__global__ __launch_bounds__(256) void prologue_kernel(
    const float* __restrict__ W1l, const float* __restrict__ W1r,
    const float* __restrict__ W2l, const float* __restrict__ W2r,
    const float* __restrict__ W3,  const float* __restrict__ x,
    unsigned short* __restrict__ wb,   // 5 weight dsts contiguous
    unsigned short* __restrict__ xb,
    unsigned char* __restrict__ x8a, unsigned char* __restrict__ x8b,
    int* __restrict__ deg, int NX4, int ND4)
{
    int i = blockIdx.x * 256 + threadIdx.x;
    if (i < WSEG) {
        const float* s; int l;
        if (i < 8192)       { if (i < 4096) { s = W1l; l = i; }
                              else          { s = W1r; l = i - 4096; } }
        else if (i < 16384) { if (i < 12288){ s = W2l; l = i - 8192; }
                              else          { s = W2r; l = i - 12288; } }
        else                { s = W3; l = i - 16384; }
        ((ushort4*)wb)[i] = cvt4h(((const float4*)s)[l]);
        return;
    }
    int j = i - WSEG;
    if (j < NX4) {
        float4 v = ((const float4*)x)[j];
        ((ushort4*)xb)[j] = cvt4h(v);
        unsigned u8 = __builtin_amdgcn_cvt_pk_fp8_f32(v.x, v.y, 0, false);
        u8 = __builtin_amdgcn_cvt_pk_fp8_f32(v.z, v.w, u8, true);
        const int n = j >> 5, g = j & 31;          // 4-col group
        if (g < 16) ((unsigned*)x8a)[n * 16 + g] = u8;
        else        ((unsigned*)x8b)[n * 16 + (g - 16)] = u8;
        return;
    }
    int k = j - NX4;
    if (k < ND4) ((int4*)deg)[k] = make_int4(0, 0, 0, 0);
}

// ---------------------------------------------------------------------------
// CSR build step 1: degree histogram over dst
__global__ __launch_bounds__(256) void hist_kernel(const int* __restrict__ dst,
                                                   int* __restrict__ deg, int E) {
    int e = blockIdx.x * 256 + threadIdx.x;
    if (e < E) atomicAdd(deg + dst[e], 1);
}

// CSR scan A: per-block sums (1024 elems/block)
__global__ __launch_bounds__(256) void scan_partial_kernel(
    const int* __restrict__ deg, int* __restrict__ partials, int N)
{
    __shared__ int ws[4];
    const int t = threadIdx.x, lane = t & 63, wave = t >> 6;
    const int i4 = blockIdx.x * 256 + t;
    const int n4 = (N + 3) / 4;
    int s = 0;
    if (i4 < n4) {
        int b = i4 * 4;
        if (b + 3 < N) {
            int4 v = ((const int4*)deg)[i4];
            s = v.x + v.y + v.z + v.w;
        } else {
            for (int q = 0; q < 4 && b + q < N; ++q) s += deg[b + q];
        }
    }
#pragma unroll
    for (int off = 32; off > 0; off >>= 1) s += __shfl_xor(s, off, 64);
    if (lane == 0) ws[wave] = s;
    __syncthreads();
    if (t == 0) partials[blockIdx.x] = ws[0] + ws[1] + ws[2] + ws[3];
}

// CSR scan B+C merged: each block redundantly reduces partials[< blockIdx]
// (P <= 64), re-scans its 1024 elems, writes rowptr & cursor.
__global__ __launch_bounds__(256) void scan_apply_kernel(
    const int* __restrict__ deg, const int* __restrict__ partials,
    int* __restrict__ rowptr, int* __restrict__ cursor, int N, int P)
{
    __shared__ int woff[4];
    __shared__ int s_base;
    const int t = threadIdx.x, lane = t & 63, wave = t >> 6;
    const int i4 = blockIdx.x * 256 + t;
    const int n4 = (N + 3) / 4;
    const int b = i4 * 4;

    if (wave == 0) {          // exclusive sum of block partials below us
        int v = (lane < P && lane < (int)blockIdx.x) ? partials[lane] : 0;
#pragma unroll
        for (int off = 32; off > 0; off >>= 1) v += __shfl_xor(v, off, 64);
        if (lane == 0) s_base = v;
    }

    int4 v = make_int4(0, 0, 0, 0);
    if (i4 < n4) {
        if (b + 3 < N) v = ((const int4*)deg)[i4];
        else {
            if (b + 0 < N) v.x = deg[b + 0];
            if (b + 1 < N) v.y = deg[b + 1];
            if (b + 2 < N) v.z = deg[b + 2];
        }
    }
    const int p1 = v.x, p2 = v.x + v.y, p3 = v.x + v.y + v.z;
    const int tsum = p3 + v.w;
    int incl = tsum;
#pragma unroll
    for (int off = 1; off < 64; off <<= 1) {
        int tt = __shfl_up(incl, off, 64);
        if (lane >= off) incl += tt;
    }
    const int texcl = incl - tsum;
    if (lane == 63) woff[wave] = incl;
    __syncthreads();
    int wo = 0;
#pragma unroll
    for (int w = 0; w < 4; ++w) if (w < wave) wo += woff[w];
    const int e = s_base + wo + texcl;
    if (blockIdx.x == 0 && t == 0) rowptr[0] = 0;
    if (b + 3 < N) {
        ((int4*)cursor)[i4] = make_int4(e, e + p1, e + p2, e + p3);
        rowptr[b + 1] = e + p1;
        rowptr[b + 2] = e + p2;
        rowptr[b + 3] = e + p3;
        rowptr[b + 4] = e + tsum;
    } else if (b < N) {
        if (b + 0 < N) { cursor[b + 0] = e;      rowptr[b + 1] = e + p1; }
        if (b + 1 < N) { cursor[b + 1] = e + p1; rowptr[b + 2] = e + p2; }
        if (b + 2 < N) { cursor[b + 2] = e + p2; rowptr[b + 3] = e + p3; }
    }
}

// CSR build: scatter src ids into neighbor lists
__global__ __launch_bounds__(256) void fill_kernel(const int* __restrict__ src,
                                                   const int* __restrict__ dst,
                                                   int* __restrict__ cursor,
                                                   int* __restrict__ csr, int E) {
    int e = blockIdx.x * 256 + threadIdx.x;
    if (e >= E) return;
    int pos = atomicAdd(cursor + dst[e], 1);
    csr[pos] = src[e];
}

// ---------------------------------------------------------------------------
// Fused SAGE layer (+optional head): 256 threads = 4 waves per 16-row tile.
// Gather tables are SPLIT into two [N,64] fp8 halves (3.2MB each, fits
// per-XCD L2). Phase 1, per half h:
//   warm: blocks with the same (blockIdx&7) share an XCD (round-robin
//     dispatch heuristic); each streams its stripe of the half-table with
//     dense dwordx4 loads -> the half lands in this XCD's L2 at streaming BW.
//   gather: lane = (slot grp = lane>>3 in [0,8), col = lane&7 covering 8 fp8
//     cols / 8B); one dwordx2 wave-load fetches EIGHT 64B neighbor rows, ~all
//     L2 hits. 16 nbrs in flight; OOB zero-masked; shfl_xor(8/16/32) reduce;
//     grp==0 lanes write the f16 half-mean (16B) to LDS.
// Phase 2: wave w computes col-tiles {2w,2w+1} (dual Wl/Wr MFMA,
//   mfma_f32_16x16x32_f16), A from LDS, self f16 from global.
//   !HEAD: store f16 out (+split fp8 copies if WFP8). HEAD: h2 -> LDS,
//   barrier, each wave one 16-col head tile (A=sh2, B=W3) -> fp32 out.
template <bool WFP8, bool HEAD>
__global__ __launch_bounds__(256) void sage_layer_kernel(
    const unsigned short* __restrict__ feat,   // [N,128] f16 (self path)
    const unsigned char* __restrict__ t0a,     // [N,64] fp8 cols 0-63
    const unsigned char* __restrict__ t1a,     // [N,64] fp8 cols 64-127
    const int* __restrict__ rowptr, const int* __restrict__ csr,
    const unsigned short* __restrict__ Wl,
    const unsigned short* __restrict__ Wr,
    const float* __restrict__ bias,
    unsigned short* __restrict__ out,          // [N,128] f16 (if !HEAD)
    unsigned char* __restrict__ o8a,           // [N,64] fp8 (if WFP8)
    unsigned char* __restrict__ o8b,           // [N,64] fp8 (if WFP8)
    const unsigned short* __restrict__ W3,     // [64,128] f16 (if HEAD)
    const float* __restrict__ b3,              // [64] (if HEAD)
    float* __restrict__ outF,                  // [N,64] fp32 (if HEAD)
    int N)
{
    __shared__ unsigned short smean[16][136];
    __shared__ unsigned short sh2[HEAD ? 16 : 1][136];
    const int wave = threadIdx.x >> 6;
    const int lane = threadIdx.x & 63;
    const int r0 = blockIdx.x * 16;

    // ---- phase 1 ----
    {
        const int grp = lane >> 3;          // neighbor slot 0..7
        const int col = lane & 7;           // 8-col group (8B of fp8)
        const int nstripe = (gridDim.x + 7) >> 3;      // blocks per XCD
        const int stripe = blockIdx.x >> 3;            // stripe within XCD

        // rowptr window (wave-uniform -> scalar loads)
        int w[5];
#pragma unroll
        for (int q = 0; q < 5; ++q) {
            int n = r0 + wave * 4 + q;
            w[q] = rowptr[n < N ? n : N];
        }

#pragma unroll
        for (int h = 0; h < 2; ++h) {
            const unsigned char* tab = h ? t1a : t0a;

            // --- warm this XCD's L2 with the half-table (streaming) ---
            {
                const uint4* t4 = (const uint4*)tab;
                const int M = N * 4;                       // uint4 count
                const int share = (M + nstripe - 1) / nstripe;
                const int s0 = stripe * share;
                const int s1 = min(s0 + share, M);
                unsigned acc = 0;
                for (int i = s0 + (int)threadIdx.x; i < s1; i += 256) {
                    uint4 v = t4[i];
                    acc ^= v.x ^ v.y ^ v.z ^ v.w;
                }
                if (acc == 0x13371337u) smean[0][0] ^= 1;  // keep-alive
            }

            // --- gather this half for the wave's 4 nodes ---
            const unsigned char* tq = tab + col * 8;
#pragma unroll
            for (int q = 0; q < 4; ++q) {
                const int mi = wave * 4 + q;
                const int n = r0 + mi;
                if (n >= N) break;
                const int beg = w[q], end = w[q + 1];
                const int deg = end - beg;
                floatx2 a0 = (floatx2)(0.f), a1 = (floatx2)(0.f);
                floatx2 a2 = (floatx2)(0.f), a3 = (floatx2)(0.f);
                for (int jA = beg + grp; jA < end; jA += 16) {
                    const int jB = jA + 8;
                    const unsigned mB = (jB < end) ? 0xffffffffu : 0u;
                    const int iA = csr[jA];
                    const int iB = csr[mB ? jB : beg];
                    uint2 pA = *(const uint2*)(tq + (size_t)iA * 64);
                    uint2 pB = *(const uint2*)(tq + (size_t)iB * 64);
                    pB.x &= mB; pB.y &= mB;
                    a0 += __builtin_amdgcn_cvt_pk_f32_fp8(pA.x, false);
                    a1 += __builtin_amdgcn_cvt_pk_f32_fp8(pA.x, true);
                    a2 += __builtin_amdgcn_cvt_pk_f32_fp8(pA.y, false);
                    a3 += __builtin_amdgcn_cvt_pk_f32_fp8(pA.y, true);
                    a0 += __builtin_amdgcn_cvt_pk_f32_fp8(pB.x, false);
                    a1 += __builtin_amdgcn_cvt_pk_f32_fp8(pB.x, true);
                    a2 += __builtin_amdgcn_cvt_pk_f32_fp8(pB.y, false);
                    a3 += __builtin_amdgcn_cvt_pk_f32_fp8(pB.y, true);
                }
                __half2 c0 = __floats2half2_rn(a0.x, a0.y);
                __half2 c1 = __floats2half2_rn(a1.x, a1.y);
                __half2 c2 = __floats2half2_rn(a2.x, a2.y);
                __half2 c3 = __floats2half2_rn(a3.x, a3.y);
                c0 = __hadd2(c0, shx(c0, 8));
                c0 = __hadd2(c0, shx(c0, 16));
                c0 = __hadd2(c0, shx(c0, 32));
                c1 = __hadd2(c1, shx(c1, 8));
                c1 = __hadd2(c1, shx(c1, 16));
                c1 = __hadd2(c1, shx(c1, 32));
                c2 = __hadd2(c2, shx(c2, 8));
                c2 = __hadd2(c2, shx(c2, 16));
                c2 = __hadd2(c2, shx(c2, 32));
                c3 = __hadd2(c3, shx(c3, 8));
                c3 = __hadd2(c3, shx(c3, 16));
                c3 = __hadd2(c3, shx(c3, 32));
                if (grp == 0) {
                    const float inv = (deg > 0) ? 1.0f / (float)deg : 0.0f;
                    uint4 o;
                    o.x = h2u(__floats2half2_rn(__low2float(c0) * inv,
                                                __high2float(c0) * inv));
                    o.y = h2u(__floats2half2_rn(__low2float(c1) * inv,
                                                __high2float(c1) * inv));
                    o.z = h2u(__floats2half2_rn(__low2float(c2) * inv,
                                                __high2float(c2) * inv));
                    o.w = h2u(__floats2half2_rn(__low2float(c3) * inv,
                                                __high2float(c3) * inv));
                    *(uint4*)&smean[mi][h * 64 + col * 8] = o;
                }
            }
        }
    }
    __syncthreads();

    // ---- phase 2: this wave computes col-tiles 2*wave, 2*wave+1 ----
    const int mrow = lane & 15;
    const int quad = lane >> 4;
    int selfRow = r0 + mrow;
    if (selfRow >= N) selfRow = N - 1;      // partial-tile clamp (loads only)
    const size_t rowS = (size_t)selfRow * 128;

    floatx4 acc0 = (floatx4)(0.0f), acc1 = (floatx4)(0.0f);
    const int t0 = wave * 2, t1 = wave * 2 + 1;

#pragma unroll
    for (int kk = 0; kk < 4; ++kk) {
        const int k = kk * 32 + quad * 8;
        f16x8 aA = *(const f16x8*)&smean[mrow][k];
        f16x8 aS = *(const f16x8*)(feat + rowS + k);
        f16x8 bl0 = *(const f16x8*)(Wl + (size_t)(t0 * 16 + mrow) * 128 + k);
        acc0 = __builtin_amdgcn_mfma_f32_16x16x32_f16(aA, bl0, acc0, 0, 0, 0);
        f16x8 br0 = *(const f16x8*)(Wr + (size_t)(t0 * 16 + mrow) * 128 + k);
        acc0 = __builtin_amdgcn_mfma_f32_16x16x32_f16(aS, br0, acc0, 0, 0, 0);
        f16x8 bl1 = *(const f16x8*)(Wl + (size_t)(t1 * 16 + mrow) * 128 + k);
        acc1 = __builtin_amdgcn_mfma_f32_16x16x32_f16(aA, bl1, acc1, 0, 0, 0);
        f16x8 br1 = *(const f16x8*)(Wr + (size_t)(t1 * 16 + mrow) * 128 + k);
        acc1 = __builtin_amdgcn_mfma_f32_16x16x32_f16(aS, br1, acc1, 0, 0, 0);
    }

    const float b0 = bias[t0 * 16 + mrow];
    const float b1 = bias[t1 * 16 + mrow];
#pragma unroll
    for (int i = 0; i < 4; ++i) {
        const int r = r0 + quad * 4 + i;
        const float v0 = fmaxf(acc0[i] + b0, 0.0f);
        const float v1 = fmaxf(acc1[i] + b1, 0.0f);
        if (HEAD) {
            sh2[quad * 4 + i][t0 * 16 + mrow] = f2h(v0);
            sh2[quad * 4 + i][t1 * 16 + mrow] = f2h(v1);
        } else if (r < N) {
            out[(size_t)r * 128 + t0 * 16 + mrow] = f2h(v0);
            out[(size_t)r * 128 + t1 * 16 + mrow] = f2h(v1);
            if (WFP8) {
                const int c0i = t0 * 16 + mrow, c1i = t1 * 16 + mrow;
                unsigned char* d0 = (c0i < 64) ? (o8a + (size_t)r * 64 + c0i)
                                               : (o8b + (size_t)r * 64 + c0i - 64);
                unsigned char* d1 = (c1i < 64) ? (o8a + (size_t)r * 64 + c1i)
                                               : (o8b + (size_t)r * 64 + c1i - 64);
                *d0 = f2fp8(v0);
                *d1 = f2fp8(v1);
            }
        }
    }

    // ---- optional fused head: out = h2 @ W3^T + b3 (fp32, 64 cols) ----
    if (HEAD) {
        __syncthreads();
        floatx4 ah = (floatx4)(0.0f);
#pragma unroll
        for (int kk = 0; kk < 4; ++kk) {
            const int k = kk * 32 + quad * 8;
            f16x8 aA = *(const f16x8*)&sh2[mrow][k];
            f16x8 b = *(const f16x8*)(W3 + (size_t)(wave * 16 + mrow) * 128 + k);
            ah = __builtin_amdgcn_mfma_f32_16x16x32_f16(aA, b, ah, 0, 0, 0);
        }
        const float bh = b3[wave * 16 + mrow];
#pragma unroll
        for (int i = 0; i < 4; ++i) {
            const int r = r0 + quad * 4 + i;
            if (r < N)
                outF[(size_t)r * 64 + wave * 16 + mrow] = ah[i] + bh;
        }
    }
}

// ---------------------------------------------------------------------------
extern "C" void kernel_launch(void* const* d_in, const int* in_sizes, int n_in,
                              void* d_out, int out_size, void* d_ws, size_t ws_size,
                              hipStream_t stream)
{
    const float* x   = (const float*)d_in[0];
    const int* ei    = (const int*)d_in[1];
    const float* W1l = (const float*)d_in[2];
    const float* b1l = (const float*)d_in[3];
    const float* W1r = (const float*)d_in[4];
    const float* W2l = (const float*)d_in[5];
    const float* b2l = (const float*)d_in[6];
    const float* W2r = (const float*)d_in[7];
    const float* W3  = (const float*)d_in[8];
    const float* b3  = (const float*)d_in[9];
    float* out = (float*)d_out;

    const int N = in_sizes[0] / 128;   // 50000
    const int E = in_sizes[1] / 2;     // 640000
    const int* src = ei;
    const int* dst = ei + E;

    // workspace layout (all offsets 16B aligned):
    //   deg_i : n4*4 ints        partials: 64 ints
    //   rowptr: N+4 ints         cursor  : n4*4 ints
    //   csr   : E ints           xb/h1   : N*128 f16 each
    //   wb    : 5 f16 weight mats contiguous
    //   x8a/x8b/h8a/h8b : N*64 fp8 each (split gather tables, 3.2MB ea)
    const int n4 = (N + 3) / 4;
    int* deg_i    = (int*)d_ws;
    int* partials = deg_i + n4 * 4;
    int* rowptr   = partials + 64;
    int* cursor   = rowptr + N + 4;
    int* csr      = cursor + n4 * 4;
    unsigned short* xb   = (unsigned short*)(csr + E);
    unsigned short* h1   = xb + (size_t)N * 128;
    unsigned short* wb1l = h1 + (size_t)N * 128;
    unsigned short* wb1r = wb1l + 16384;
    unsigned short* wb2l = wb1r + 16384;
    unsigned short* wb2r = wb2l + 16384;
    unsigned short* wb3  = wb2r + 16384;
    unsigned char* x8a   = (unsigned char*)(wb3 + 8192);
    unsigned char* x8b   = x8a + (size_t)N * 64;
    unsigned char* h8a   = x8b + (size_t)N * 64;
    unsigned char* h8b   = h8a + (size_t)N * 64;

    const int lblk = (N + 15) / 16;             // fused layer: 1 tile/block
    const int eblk = (E + 255) / 256;
    const int NX4  = N * 32;                    // x in float4 units
    const int P    = (n4 + 255) / 256;          // scan blocks (<=64 for N<=65536)

    // ---- fused prologue: weight cvt + x cvt (f16 + split fp8) + deg zero ----
    {
        int total = WSEG + NX4 + n4;
        hipLaunchKernelGGL(prologue_kernel, dim3((total + 255) / 256), dim3(256), 0,
                           stream, W1l, W1r, W2l, W2r, W3, x, wb1l, xb, x8a, x8b,
                           deg_i, NX4, n4);
    }

    // ---- CSR build (once; reused by both layers) ----
    hipLaunchKernelGGL(hist_kernel, dim3(eblk), dim3(256), 0, stream, dst, deg_i, E);
    hipLaunchKernelGGL(scan_partial_kernel, dim3(P), dim3(256), 0, stream,
                       deg_i, partials, N);
    hipLaunchKernelGGL(scan_apply_kernel, dim3(P), dim3(256), 0, stream,
                       deg_i, partials, rowptr, cursor, N, P);
    hipLaunchKernelGGL(fill_kernel, dim3(eblk), dim3(256), 0, stream,
                       src, dst, cursor, csr, E);

    // ---- fused layers (layer 2 carries the head) ----
    hipLaunchKernelGGL((sage_layer_kernel<true, false>), dim3(lblk), dim3(256), 0,
                       stream, xb, x8a, x8b, rowptr, csr, wb1l, wb1r, b1l,
                       h1, h8a, h8b, nullptr, nullptr, nullptr, N);
    hipLaunchKernelGGL((sage_layer_kernel<false, true>), dim3(lblk), dim3(256), 0,
                       stream, h1, h8a, h8b, rowptr, csr, wb2l, wb2r, b2l,
                       nullptr, nullptr, nullptr, wb3, b3, out, N);
}